// Round 11
// baseline (233.317 us; speedup 1.0000x reference)
//
#include <hip/hip_runtime.h>
#include <stdint.h>
#include <math.h>

typedef __attribute__((ext_vector_type(8))) short short8;
typedef __attribute__((ext_vector_type(4))) float f32x4;
typedef __attribute__((ext_vector_type(4))) ushort ushort4v;

__device__ __forceinline__ ushort f2bf(float f) {
    union { float f; uint32_t i; } v; v.f = f;
    uint32_t r = v.i + 0x7FFFu + ((v.i >> 16) & 1u);
    return (ushort)(r >> 16);
}
__device__ __forceinline__ float bf2f(ushort u) {
    union { uint32_t i; float f; } v; v.i = ((uint32_t)u) << 16; return v.f;
}

// async global->LDS, 16B per lane. LDS dest is wave-uniform base + lane*16.
__device__ __forceinline__ void gload_lds16(const ushort* gp, ushort* lp) {
    __builtin_amdgcn_global_load_lds(
        (const __attribute__((address_space(1))) void*)gp,
        (__attribute__((address_space(3))) void*)lp, 16, 0, 0);
}

// ---------------------------------------------------------------------------
// Kernel 1: input transpose [B,T,C,L] (f32) -> x[token][c] (f32) + LN1 -> xln (bf16)
__global__ __launch_bounds__(512) void prep_kernel(const float* __restrict__ in,
        const float* __restrict__ g, const float* __restrict__ bta,
        float* __restrict__ x, ushort* __restrict__ xln) {
    int token = blockIdx.x;          // 0..4095
    int c = threadIdx.x;             // 0..511
    int b = token >> 11;
    int n = token & 2047;
    int t = n >> 8;
    int l = n & 255;
    size_t iidx = (((size_t)((b * 8 + t) * 512 + c)) << 8) + l;
    float v = in[iidx];
    x[(size_t)token * 512 + c] = v;

    float s = v, s2 = v * v;
    #pragma unroll
    for (int off = 32; off > 0; off >>= 1) {
        s  += __shfl_down(s, off, 64);
        s2 += __shfl_down(s2, off, 64);
    }
    __shared__ float ps[8], ps2[8];
    int wave = threadIdx.x >> 6, lane = threadIdx.x & 63;
    if (lane == 0) { ps[wave] = s; ps2[wave] = s2; }
    __syncthreads();
    float mu = 0.f, m2 = 0.f;
    #pragma unroll
    for (int i = 0; i < 8; i++) { mu += ps[i]; m2 += ps2[i]; }
    mu *= (1.0f / 512.0f); m2 *= (1.0f / 512.0f);
    float rs = rsqrtf(m2 - mu * mu + 1e-5f);
    float y = (v - mu) * rs * g[c] + bta[c];
    xln[(size_t)token * 512 + c] = f2bf(y);
}

// ---------------------------------------------------------------------------
// LN2 over f32 input -> bf16
__global__ __launch_bounds__(512) void ln2_kernel(const float* __restrict__ xin,
        const float* __restrict__ g, const float* __restrict__ bta,
        ushort* __restrict__ out) {
    int token = blockIdx.x;
    int c = threadIdx.x;
    float v = xin[(size_t)token * 512 + c];
    float s = v, s2 = v * v;
    #pragma unroll
    for (int off = 32; off > 0; off >>= 1) {
        s  += __shfl_down(s, off, 64);
        s2 += __shfl_down(s2, off, 64);
    }
    __shared__ float ps[8], ps2[8];
    int wave = threadIdx.x >> 6, lane = threadIdx.x & 63;
    if (lane == 0) { ps[wave] = s; ps2[wave] = s2; }
    __syncthreads();
    float mu = 0.f, m2 = 0.f;
    #pragma unroll
    for (int i = 0; i < 8; i++) { mu += ps[i]; m2 += ps2[i]; }
    mu *= (1.0f / 512.0f); m2 *= (1.0f / 512.0f);
    float rs = rsqrtf(m2 - mu * mu + 1e-5f);
    float y = (v - mu) * rs * g[c] + bta[c];
    out[(size_t)token * 512 + c] = f2bf(y);
}

// ---------------------------------------------------------------------------
// Fused weight transpose+convert: Bw f32 [K][N] -> Bt bf16 [N][K].
__global__ __launch_bounds__(256) void wtrans_kernel(
        const float* __restrict__ wa, ushort* __restrict__ ta,
        const float* __restrict__ wb, ushort* __restrict__ tb,
        const float* __restrict__ wc, ushort* __restrict__ tc,
        const float* __restrict__ wd, ushort* __restrict__ td) {
    __shared__ float tile[32][33];
    int bid = blockIdx.x;
    const float* W; ushort* T; int K, N, tn, tk;
    if (bid < 768)       { W = wa; T = ta; K = 512;  N = 1536; tn = bid % 48; tk = bid / 48; }
    else if (bid < 1024) { bid -= 768;  W = wb; T = tb; K = 512;  N = 512;  tn = bid % 16; tk = bid / 16; }
    else if (bid < 2048) { bid -= 1024; W = wc; T = tc; K = 512;  N = 2048; tn = bid % 64; tk = bid / 64; }
    else                 { bid -= 2048; W = wd; T = td; K = 2048; N = 512;  tn = bid % 16; tk = bid / 16; }
    int n0 = tn * 32, k0 = tk * 32;
    int tx = threadIdx.x & 31, ty = threadIdx.x >> 5;   // 32 x 8
    #pragma unroll
    for (int i = 0; i < 4; i++)
        tile[ty + i * 8][tx] = W[(size_t)(k0 + ty + i * 8) * N + n0 + tx];
    __syncthreads();
    #pragma unroll
    for (int i = 0; i < 4; i++) {
        int nn = ty + i * 8;
        T[(size_t)(n0 + nn) * K + k0 + tx] = f2bf(tile[tx][nn]);
    }
}

// ---------------------------------------------------------------------------
// MFMA GEMM, 2-phase stage-early double buffer (T3-minimum recipe, race-free):
// C = A[MxK](bf16) @ Bt[N][K](bf16) + bias. BMx128 tile, BK=64, 4 waves.
// LINEAR global_load_lds staging (FETCH-clean, round 9 verified).
// Per tile: (1) issue next tile's loads into buf cur^1, (2) compute buf cur,
// (3) ONE __syncthreads -- its built-in vmcnt(0) drain lands tile t+1, whose
// latency was covered by the compute phase. Correctness rests only on
// __syncthreads ordering (stage targets cur^1, last read before the PREVIOUS
// barrier) -- no vmcnt counting, cannot race (round 10 lesson / m152).
// BM=128: 2x2 waves, 64x64 each (32 MFMA/tile, longer cover). BM=64: 1x4
// waves, 64x32 each (for N=512 GEMMs -> 256+ block grids, 3 blocks/CU).
// EPI_F32PART: split-K partial (gridDim.z=2) -> raw f32 partials -> tout.
#define EPI_BF16    0
#define EPI_F32RES  1
#define EPI_GELU    2
#define EPI_F32PART 3

template<int EPI, int BM>
__global__ __launch_bounds__(256) void gemm_kernel(
        const ushort* __restrict__ A, const ushort* __restrict__ Bt,
        const float* __restrict__ bias, const float* __restrict__ resid,
        float* __restrict__ outF, float* __restrict__ outF2,
        ushort* __restrict__ outB, int M, int N, int K) {
    __shared__ __align__(16) ushort As[2][BM * 64];    // 2 x (BM rows x 128B)
    __shared__ __align__(16) ushort Bs[2][128 * 64];   // 2 x 16 KB
    int tid = threadIdx.x;
    int wave = tid >> 6, lane = tid & 63;
    int l16 = lane & 15, quad = lane >> 4;
    constexpr int NJ = (BM == 128) ? 4 : 2;
    constexpr int WCW = (BM == 128) ? 64 : 32;      // wave col width
    int wr = (BM == 128) ? (wave >> 1) : 0;
    int wc = (BM == 128) ? (wave & 1) : wave;
    int m0 = blockIdx.y * BM, n0 = blockIdx.x * 128;
    int Ksp = K / gridDim.z;             // split-K span (z=1 -> full K)
    int kbeg = blockIdx.z * Ksp;

    auto stage = [&](int bi, int k0) {   // linear: lanes ch++ -> contiguous 128B
        #pragma unroll
        for (int c = 0; c < BM / 32; c++) {
            int slot = c * 256 + tid;
            int row = slot >> 3, ch = slot & 7;
            gload_lds16(A + (size_t)(m0 + row) * K + k0 + ch * 8,
                        &As[bi][(c * 256 + wave * 64) * 8]);
        }
        #pragma unroll
        for (int c = 0; c < 4; c++) {
            int slot = c * 256 + tid;
            int row = slot >> 3, ch = slot & 7;
            gload_lds16(Bt + (size_t)(n0 + row) * K + k0 + ch * 8,
                        &Bs[bi][(c * 256 + wave * 64) * 8]);
        }
    };

    f32x4 acc[4][NJ] = {};
    int nt = Ksp >> 6;
    stage(0, kbeg);
    __syncthreads();                     // tile 0 landed (vmcnt(0) drain inside)
    for (int t = 0; t < nt; ++t) {
        int cur = t & 1;
        if (t + 1 < nt) stage(cur ^ 1, kbeg + ((t + 1) << 6));  // issue EARLY
        __builtin_amdgcn_sched_barrier(0);   // pin loads before compute
        #pragma unroll
        for (int kk = 0; kk < 2; kk++) {
            short8 af[4], bf[NJ];
            #pragma unroll
            for (int i = 0; i < 4; i++)
                af[i] = *(const short8*)&As[cur][(wr * 64 + i * 16 + l16) * 64 + kk * 32 + quad * 8];
            #pragma unroll
            for (int j = 0; j < NJ; j++)
                bf[j] = *(const short8*)&Bs[cur][(wc * WCW + j * 16 + l16) * 64 + kk * 32 + quad * 8];
            #pragma unroll
            for (int i = 0; i < 4; i++)
                #pragma unroll
                for (int j = 0; j < NJ; j++)
                    acc[i][j] = __builtin_amdgcn_mfma_f32_16x16x32_bf16(af[i], bf[j], acc[i][j], 0, 0, 0);
        }
        __syncthreads();   // drains vmcnt(0): tile t+1 in LDS; all reads of cur done
    }
    // epilogue: C frag layout col=l16, row=quad*4+r
    float* oP = (EPI == EPI_F32PART && blockIdx.z == 1) ? outF2 : outF;
    #pragma unroll
    for (int i = 0; i < 4; i++) {
        int row_base = m0 + wr * 64 + i * 16 + quad * 4;
        #pragma unroll
        for (int j = 0; j < NJ; j++) {
            int col = n0 + wc * WCW + j * 16 + l16;
            float bvf = (EPI == EPI_F32PART) ? 0.f : bias[col];
            #pragma unroll
            for (int r = 0; r < 4; r++) {
                int row = row_base + r;
                float v = acc[i][j][r] + bvf;
                if constexpr (EPI == EPI_F32RES) {
                    outF[(size_t)row * N + col] = v + resid[(size_t)row * N + col];
                } else if constexpr (EPI == EPI_F32PART) {
                    oP[(size_t)row * N + col] = v;
                } else if constexpr (EPI == EPI_GELU) {
                    float gg = 0.5f * v * (1.0f + erff(v * 0.70710678118654752f));
                    outB[(size_t)row * N + col] = f2bf(gg);
                } else {
                    outB[(size_t)row * N + col] = f2bf(v);
                }
            }
        }
    }
}

// ---------------------------------------------------------------------------
// Flash attention, split-K in block, swapped-operand QK^T (round-9 version,
// best measured 48.7 us -- byte-identical).
__global__ __launch_bounds__(512) void flash_kernel(const ushort* __restrict__ qkv,
        ushort* __restrict__ o) {
    __shared__ __align__(16) char smem[47232];
    auto Ks  = (ushort (*)[64][72])smem;              // [kh][key][d]   18432 B
    auto Vt  = (ushort (*)[4640])(smem + 18432);      // [kh][VT(d,key)] 18560 B
    auto Pt  = (ushort (*)[16][40])(smem + 36992);    // [wave][q][32key+pad] 10240 B
    auto cbuf = (float (*)[18][64])smem;              // combine buffer (aliased)
    // VT(d,key) = d*72 + (d>>4)*8 + key

    int tid = threadIdx.x;
    int wave = tid >> 6, lane = tid & 63;
    int kh = wave >> 2;          // key half this wave owns
    int wq = wave & 3;           // 16-q-row group
    int l16 = lane & 15, quad = lane >> 4;
    int bidx = blockIdx.x;
    int qt = bidx & 31;
    int h = (bidx >> 5) & 7;
    int b = bidx >> 8;
    int q0 = qt * 64;
    const size_t base = (size_t)b * 2048 * 1536;

    int htid = tid & 255;
    int srow = htid >> 2;            // key row 0..63
    int sg   = htid & 3;             // d-chunk 0..3
    int sdb  = sg * 16;
    const ushort* kgbase = qkv + base + 512  + h * 64 + sdb;
    const ushort* vgbase = qkv + base + 1024 + h * 64 + sdb;
    int vldsoff = sdb * 72 + sg * 8 + srow;

    short8 aq[2];
    {
        int qrow = q0 + wq * 16 + l16;
        const ushort* qp = qkv + base + (size_t)qrow * 1536 + h * 64;
        aq[0] = *(const short8*)(qp + quad * 8);
        aq[1] = *(const short8*)(qp + 32 + quad * 8);
    }
    f32x4 accO[4] = {};
    float mrow = -INFINITY, lrow = 0.f;   // per-lane state for q = l16

    {   // prologue: stage tile 0
        int kb = kh * 1024;
        const ushort* kp = kgbase + (size_t)(kb + srow) * 1536;
        short8 k0 = *(const short8*)kp;
        short8 k1 = *(const short8*)(kp + 8);
        const ushort* vp = vgbase + (size_t)(kb + srow) * 1536;
        short8 v0 = *(const short8*)vp;
        short8 v1 = *(const short8*)(vp + 8);
        *(short8*)&Ks[kh][srow][sdb]     = k0;
        *(short8*)&Ks[kh][srow][sdb + 8] = k1;
        #pragma unroll
        for (int i = 0; i < 8; i++) Vt[kh][vldsoff + i * 72] = (ushort)v0[i];
        #pragma unroll
        for (int i = 0; i < 8; i++) Vt[kh][vldsoff + (8 + i) * 72] = (ushort)v1[i];
    }
    __syncthreads();

    for (int it = 0; it < 16; ++it) {
        short8 nk0, nk1, nv0, nv1;
        bool pre = (it < 15);
        if (pre) {   // prefetch next tile -> regs; latency hides under compute
            int kb = kh * 1024 + (it + 1) * 64;
            const ushort* kp = kgbase + (size_t)(kb + srow) * 1536;
            nk0 = *(const short8*)kp;
            nk1 = *(const short8*)(kp + 8);
            const ushort* vp = vgbase + (size_t)(kb + srow) * 1536;
            nv0 = *(const short8*)vp;
            nv1 = *(const short8*)(vp + 8);
        }
        // S^T = K Q^T : lane (l16,quad) gets S[key=s*16+quad*4+r][q=l16]
        f32x4 sacc[4] = {};
        __builtin_amdgcn_s_setprio(1);
        #pragma unroll
        for (int c = 0; c < 2; c++) {
            #pragma unroll
            for (int s = 0; s < 4; s++) {
                short8 kf = *(short8*)&Ks[kh][s * 16 + l16][c * 32 + quad * 8];
                sacc[s] = __builtin_amdgcn_mfma_f32_16x16x32_bf16(kf, aq[c], sacc[s], 0, 0, 0);
            }
        }
        __builtin_amdgcn_s_setprio(0);
        // online softmax: per-lane row, reduce across the 4 quads
        float tm = sacc[0][0];
        #pragma unroll
        for (int s = 0; s < 4; s++)
            #pragma unroll
            for (int r = 0; r < 4; r++) tm = fmaxf(tm, sacc[s][r]);
        tm = fmaxf(tm, __shfl_xor(tm, 16, 64));
        tm = fmaxf(tm, __shfl_xor(tm, 32, 64));
        float mn = fmaxf(mrow, tm * 0.125f);
        float al = __expf(mrow - mn);
        float rsum = 0.f;
        ushort4v w4[4];
        #pragma unroll
        for (int s = 0; s < 4; s++)
            #pragma unroll
            for (int r = 0; r < 4; r++) {
                float pv = __expf(sacc[s][r] * 0.125f - mn);
                rsum += pv;
                w4[s][r] = f2bf(pv);
            }
        rsum += __shfl_xor(rsum, 16, 64);
        rsum += __shfl_xor(rsum, 32, 64);
        lrow = lrow * al + rsum;
        mrow = mn;
        #pragma unroll
        for (int s = 0; s < 4; s++)
            #pragma unroll
            for (int r = 0; r < 4; r++) accO[s][r] *= al;
        // P -> Pt (packed b64), double-pumped half tile; PV = mfma(V^T, P)
        *(ushort4v*)&Pt[wave][l16][quad * 4]      = w4[0];
        *(ushort4v*)&Pt[wave][l16][16 + quad * 4] = w4[1];
        {
            short8 ap = *(short8*)&Pt[wave][l16][quad * 8];
            __builtin_amdgcn_s_setprio(1);
            #pragma unroll
            for (int s = 0; s < 4; s++) {
                short8 vf = *(short8*)&Vt[kh][(s * 16 + l16) * 72 + s * 8 + quad * 8];
                accO[s] = __builtin_amdgcn_mfma_f32_16x16x32_bf16(vf, ap, accO[s], 0, 0, 0);
            }
            __builtin_amdgcn_s_setprio(0);
        }
        *(ushort4v*)&Pt[wave][l16][quad * 4]      = w4[2];
        *(ushort4v*)&Pt[wave][l16][16 + quad * 4] = w4[3];
        {
            short8 ap = *(short8*)&Pt[wave][l16][quad * 8];
            __builtin_amdgcn_s_setprio(1);
            #pragma unroll
            for (int s = 0; s < 4; s++) {
                short8 vf = *(short8*)&Vt[kh][(s * 16 + l16) * 72 + s * 8 + 32 + quad * 8];
                accO[s] = __builtin_amdgcn_mfma_f32_16x16x32_bf16(vf, ap, accO[s], 0, 0, 0);
            }
            __builtin_amdgcn_s_setprio(0);
        }
        __syncthreads();   // all waves done reading Ks/Vt tile it
        if (pre) {
            *(short8*)&Ks[kh][srow][sdb]     = nk0;
            *(short8*)&Ks[kh][srow][sdb + 8] = nk1;
            #pragma unroll
            for (int i = 0; i < 8; i++) Vt[kh][vldsoff + i * 72] = (ushort)nv0[i];
            #pragma unroll
            for (int i = 0; i < 8; i++) Vt[kh][vldsoff + (8 + i) * 72] = (ushort)nv1[i];
        }
        __syncthreads();
    }
    // ---- merge key-half partials (wave w with wave w+4); state is per-lane ----
    if (kh == 1) {
        cbuf[wq][0][lane] = mrow;
        cbuf[wq][1][lane] = lrow;
        #pragma unroll
        for (int s = 0; s < 4; s++)
            #pragma unroll
            for (int r = 0; r < 4; r++)
                cbuf[wq][2 + s * 4 + r][lane] = accO[s][r];
    }
    __syncthreads();
    if (kh == 0) {
        float m1 = cbuf[wq][0][lane];
        float l1 = cbuf[wq][1][lane];
        float mn = fmaxf(mrow, m1);
        float a0 = __expf(mrow - mn);
        float a1 = __expf(m1 - mn);
        float rl = 1.0f / (lrow * a0 + l1 * a1);
        int qrow = q0 + wq * 16 + l16;
        #pragma unroll
        for (int s = 0; s < 4; s++) {
            ushort4v ov4;
            #pragma unroll
            for (int r = 0; r < 4; r++) {
                float ov = (accO[s][r] * a0 + cbuf[wq][2 + s * 4 + r][lane] * a1) * rl;
                ov4[r] = f2bf(ov);
            }
            *(ushort4v*)&o[((size_t)(b * 2048 + qrow)) * 512 + h * 64 + s * 16 + quad * 4] = ov4;
        }
    }
}

// ---------------------------------------------------------------------------
// Output transpose + split-K combine: x = x2 + pA + pB + b2 (f32), then
// transpose [token][c] -> out[b,t,c,l]. LDS tiled 32x32.
__global__ __launch_bounds__(256) void tout_kernel(const float* __restrict__ x2,
        const float* __restrict__ pA, const float* __restrict__ pB,
        const float* __restrict__ b2, float* __restrict__ out) {
    __shared__ float tile[32][33];
    int bt = blockIdx.z;
    int l0 = blockIdx.y * 32;
    int c0 = blockIdx.x * 32;
    int tx = threadIdx.x, ty = threadIdx.y;   // 32 x 8
    float bv = b2[c0 + tx];
    #pragma unroll
    for (int i = 0; i < 4; i++) {
        int l = ty + i * 8;
        size_t idx = ((size_t)bt * 256 + l0 + l) * 512 + c0 + tx;
        tile[l][tx] = x2[idx] + pA[idx] + pB[idx] + bv;
    }
    __syncthreads();
    #pragma unroll
    for (int i = 0; i < 4; i++) {
        int cc = ty + i * 8;
        out[((size_t)bt * 512 + c0 + cc) * 256 + l0 + tx] = tile[tx][cc];
    }
}

// ---------------------------------------------------------------------------
extern "C" void kernel_launch(void* const* d_in, const int* in_sizes, int n_in,
                              void* d_out, int out_size, void* d_ws, size_t ws_size,
                              hipStream_t stream) {
    const float* in_feat = (const float*)d_in[0];
    const float* qkv_w  = (const float*)d_in[1];
    const float* qkv_b  = (const float*)d_in[2];
    const float* proj_w = (const float*)d_in[3];
    const float* proj_b = (const float*)d_in[4];
    const float* ln1_g  = (const float*)d_in[5];
    const float* ln1_b  = (const float*)d_in[6];
    const float* w1     = (const float*)d_in[7];
    const float* b1     = (const float*)d_in[8];
    const float* w2     = (const float*)d_in[9];
    const float* b2     = (const float*)d_in[10];
    const float* ln2_g  = (const float*)d_in[11];
    const float* ln2_b  = (const float*)d_in[12];

    char* ws = (char*)d_ws;
    float*  x    = (float*) (ws);              // 8 MB residual 1
    float*  x2   = (float*) (ws + 8388608);    // 8 MB residual 2
    ushort* xln  = (ushort*)(ws + 16777216);   // 4 MB LN1 out
    ushort* h2   = (ushort*)(ws + 20971520);   // 4 MB LN2 out
    ushort* ao   = (ushort*)(ws + 25165824);   // 4 MB attention out
    ushort* qkv  = (ushort*)(ws + 29360128);   // 12 MB qkv
    ushort* gbuf = (ushort*)(ws + 41943040);   // 16 MB MLP hidden

    // split-K partials for MLP-down: reuse dead regions (x dead after proj;
    // xln+h2 dead after QKV/up respectively)
    float* pA = (float*)(ws);                  // 8 MB over x
    float* pB = (float*)(ws + 16777216);       // 8 MB over xln+h2

    // bf16-transposed weights live in d_out (overwritten by tout at step 8)
    char* scr = (char*)d_out;
    ushort* qkvT = (ushort*)(scr);             // 1.5 MB
    ushort* projT = (ushort*)(scr + 1572864);  // 0.5 MB
    ushort* w1T  = (ushort*)(scr + 2097152);   // 2 MB
    ushort* w2T  = (ushort*)(scr + 4194304);   // 2 MB

    wtrans_kernel<<<3072, 256, 0, stream>>>(qkv_w, qkvT, proj_w, projT,
                                            w1, w1T, w2, w2T);
    prep_kernel<<<4096, 512, 0, stream>>>(in_feat, ln1_g, ln1_b, x, xln);
    // QKV: 128x128 tiles -> 384 blocks
    gemm_kernel<EPI_BF16, 128><<<dim3(12, 32), 256, 0, stream>>>(
        xln, qkvT, qkv_b, nullptr, nullptr, nullptr, qkv, 4096, 1536, 512);
    flash_kernel<<<512, 512, 0, stream>>>(qkv, ao);
    // proj + residual: 64x128 tiles -> 256 blocks
    gemm_kernel<EPI_F32RES, 64><<<dim3(4, 64), 256, 0, stream>>>(
        ao, projT, proj_b, x, x2, nullptr, nullptr, 4096, 512, 512);
    ln2_kernel<<<4096, 512, 0, stream>>>(x2, ln2_g, ln2_b, h2);
    // MLP up + GELU: 128x128 tiles -> 512 blocks
    gemm_kernel<EPI_GELU, 128><<<dim3(16, 32), 256, 0, stream>>>(
        h2, w1T, b1, nullptr, nullptr, nullptr, gbuf, 4096, 2048, 512);
    // MLP down, split-K2: 512 blocks, f32 partials combined in tout
    gemm_kernel<EPI_F32PART, 64><<<dim3(4, 64, 2), 256, 0, stream>>>(
        gbuf, w2T, nullptr, nullptr, pA, pB, nullptr, 4096, 512, 2048);
    // output transpose + combine (x2 + pA + pB + b2)
    tout_kernel<<<dim3(16, 8, 16), dim3(32, 8), 0, stream>>>(
        x2, pA, pB, b2, (float*)d_out);
}

// Round 12
// 228.891 us; speedup vs baseline: 1.0193x; 1.0193x over previous
//
#include <hip/hip_runtime.h>
#include <stdint.h>
#include <math.h>

typedef __attribute__((ext_vector_type(8))) short short8;
typedef __attribute__((ext_vector_type(4))) float f32x4;
typedef __attribute__((ext_vector_type(4))) ushort ushort4v;

__device__ __forceinline__ ushort f2bf(float f) {
    union { float f; uint32_t i; } v; v.f = f;
    uint32_t r = v.i + 0x7FFFu + ((v.i >> 16) & 1u);
    return (ushort)(r >> 16);
}
__device__ __forceinline__ float bf2f(ushort u) {
    union { uint32_t i; float f; } v; v.i = ((uint32_t)u) << 16; return v.f;
}

// ---------------------------------------------------------------------------
// Kernel 1: input transpose [B,T,C,L] (f32) -> x[token][c] (f32) + LN1 -> xln (bf16)
__global__ __launch_bounds__(512) void prep_kernel(const float* __restrict__ in,
        const float* __restrict__ g, const float* __restrict__ bta,
        float* __restrict__ x, ushort* __restrict__ xln) {
    int token = blockIdx.x;          // 0..4095
    int c = threadIdx.x;             // 0..511
    int b = token >> 11;
    int n = token & 2047;
    int t = n >> 8;
    int l = n & 255;
    size_t iidx = (((size_t)((b * 8 + t) * 512 + c)) << 8) + l;
    float v = in[iidx];
    x[(size_t)token * 512 + c] = v;

    float s = v, s2 = v * v;
    #pragma unroll
    for (int off = 32; off > 0; off >>= 1) {
        s  += __shfl_down(s, off, 64);
        s2 += __shfl_down(s2, off, 64);
    }
    __shared__ float ps[8], ps2[8];
    int wave = threadIdx.x >> 6, lane = threadIdx.x & 63;
    if (lane == 0) { ps[wave] = s; ps2[wave] = s2; }
    __syncthreads();
    float mu = 0.f, m2 = 0.f;
    #pragma unroll
    for (int i = 0; i < 8; i++) { mu += ps[i]; m2 += ps2[i]; }
    mu *= (1.0f / 512.0f); m2 *= (1.0f / 512.0f);
    float rs = rsqrtf(m2 - mu * mu + 1e-5f);
    float y = (v - mu) * rs * g[c] + bta[c];
    xln[(size_t)token * 512 + c] = f2bf(y);
}

// ---------------------------------------------------------------------------
// LN2 over f32 input -> bf16
__global__ __launch_bounds__(512) void ln2_kernel(const float* __restrict__ xin,
        const float* __restrict__ g, const float* __restrict__ bta,
        ushort* __restrict__ out) {
    int token = blockIdx.x;
    int c = threadIdx.x;
    float v = xin[(size_t)token * 512 + c];
    float s = v, s2 = v * v;
    #pragma unroll
    for (int off = 32; off > 0; off >>= 1) {
        s  += __shfl_down(s, off, 64);
        s2 += __shfl_down(s2, off, 64);
    }
    __shared__ float ps[8], ps2[8];
    int wave = threadIdx.x >> 6, lane = threadIdx.x & 63;
    if (lane == 0) { ps[wave] = s; ps2[wave] = s2; }
    __syncthreads();
    float mu = 0.f, m2 = 0.f;
    #pragma unroll
    for (int i = 0; i < 8; i++) { mu += ps[i]; m2 += ps2[i]; }
    mu *= (1.0f / 512.0f); m2 *= (1.0f / 512.0f);
    float rs = rsqrtf(m2 - mu * mu + 1e-5f);
    float y = (v - mu) * rs * g[c] + bta[c];
    out[(size_t)token * 512 + c] = f2bf(y);
}

// ---------------------------------------------------------------------------
// Fused weight transpose+convert: Bw f32 [K][N] -> Bt bf16 [N][K].
__global__ __launch_bounds__(256) void wtrans_kernel(
        const float* __restrict__ wa, ushort* __restrict__ ta,
        const float* __restrict__ wb, ushort* __restrict__ tb,
        const float* __restrict__ wc, ushort* __restrict__ tc,
        const float* __restrict__ wd, ushort* __restrict__ td) {
    __shared__ float tile[32][33];
    int bid = blockIdx.x;
    const float* W; ushort* T; int K, N, tn, tk;
    if (bid < 768)       { W = wa; T = ta; K = 512;  N = 1536; tn = bid % 48; tk = bid / 48; }
    else if (bid < 1024) { bid -= 768;  W = wb; T = tb; K = 512;  N = 512;  tn = bid % 16; tk = bid / 16; }
    else if (bid < 2048) { bid -= 1024; W = wc; T = tc; K = 512;  N = 2048; tn = bid % 64; tk = bid / 64; }
    else                 { bid -= 2048; W = wd; T = td; K = 2048; N = 512;  tn = bid % 16; tk = bid / 16; }
    int n0 = tn * 32, k0 = tk * 32;
    int tx = threadIdx.x & 31, ty = threadIdx.x >> 5;   // 32 x 8
    #pragma unroll
    for (int i = 0; i < 4; i++)
        tile[ty + i * 8][tx] = W[(size_t)(k0 + ty + i * 8) * N + n0 + tx];
    __syncthreads();
    #pragma unroll
    for (int i = 0; i < 4; i++) {
        int nn = ty + i * 8;
        T[(size_t)(n0 + nn) * K + k0 + tx] = f2bf(tile[tx][nn]);
    }
}

// ---------------------------------------------------------------------------
// MFMA GEMM, reg-staged 2-deep pipeline (race-free by dataflow):
// C = A[MxK](bf16) @ Bt[N][K](bf16) + bias. 64x128 tile, BK=64, 4 waves,
// each 64x32 (acc[4][2], 16 MFMA/tile).
// Iter t: issue tile t+2 global loads -> regs; compute tile t from LDS;
// ds_write tile t+1 regs -> LDS (compiler auto-inserts vmcnt(N) waiting ONLY
// for tile t+1's regs -- tile t+2 stays in flight); lgkmcnt(0); raw s_barrier.
// All waits are compiler data-dependence or absolute -- no hand-counted vmcnt
// (round-10's race mode is impossible). ONE barrier per tile.
// LDS rows padded to 72 ushorts (144B, 16B-aligned): ds_read_b128 lands
// 2 lanes/bank (free, m136) -- fixes the linear layout's 16-way conflict that
// becomes critical once staging is pipelined (T2 regime gate, m252).
// XCD swizzle (T1): physical p -> logical L=(p%8)*cpx+p/8; logical is x-major
// so blocks sharing a B-panel run consecutively on one XCD (B L2-resident).
#define EPI_BF16    0
#define EPI_F32RES  1
#define EPI_GELU    2
#define EPI_F32PART 3

#define GISSUE(S, KT) do { \
    pa##S##0 = *(const short8*)(agp0 + (KT)); \
    pa##S##1 = *(const short8*)(agp1 + (KT)); \
    pb##S##0 = *(const short8*)(bgp0 + (KT)); \
    pb##S##1 = *(const short8*)(bgp1 + (KT)); \
    pb##S##2 = *(const short8*)(bgp2 + (KT)); \
    pb##S##3 = *(const short8*)(bgp3 + (KT)); \
} while (0)

#define GWRITE(BUF, S) do { \
    *(short8*)&As[BUF][aw0] = pa##S##0; \
    *(short8*)&As[BUF][aw1] = pa##S##1; \
    *(short8*)&Bs[BUF][bw0] = pb##S##0; \
    *(short8*)&Bs[BUF][bw1] = pb##S##1; \
    *(short8*)&Bs[BUF][bw2] = pb##S##2; \
    *(short8*)&Bs[BUF][bw3] = pb##S##3; \
} while (0)

#define GCOMPUTE(BUF) do { \
    _Pragma("unroll") \
    for (int kk = 0; kk < 2; kk++) { \
        short8 af[4], bf[2]; \
        _Pragma("unroll") \
        for (int i = 0; i < 4; i++) \
            af[i] = *(const short8*)&As[BUF][(i * 16 + l16) * 72 + kk * 32 + quad * 8]; \
        _Pragma("unroll") \
        for (int j = 0; j < 2; j++) \
            bf[j] = *(const short8*)&Bs[BUF][(wc * 32 + j * 16 + l16) * 72 + kk * 32 + quad * 8]; \
        _Pragma("unroll") \
        for (int i = 0; i < 4; i++) \
            _Pragma("unroll") \
            for (int j = 0; j < 2; j++) \
                acc[i][j] = __builtin_amdgcn_mfma_f32_16x16x32_bf16(af[i], bf[j], acc[i][j], 0, 0, 0); \
    } \
} while (0)

#define GSYNC() do { \
    asm volatile("s_waitcnt lgkmcnt(0)" ::: "memory"); \
    __builtin_amdgcn_sched_barrier(0); \
    __builtin_amdgcn_s_barrier(); \
    __builtin_amdgcn_sched_barrier(0); \
} while (0)

template<int EPI>
__global__ __launch_bounds__(256) void gemm_kernel(
        const ushort* __restrict__ A, const ushort* __restrict__ Bt,
        const float* __restrict__ bias, const float* __restrict__ resid,
        float* __restrict__ outF, float* __restrict__ outF2,
        ushort* __restrict__ outB, int M, int N, int K) {
    __shared__ __align__(16) ushort As[2][64 * 72];    // 2 x 9 KB (pad 72)
    __shared__ __align__(16) ushort Bs[2][128 * 72];   // 2 x 18 KB
    int tid = threadIdx.x;
    int wave = tid >> 6, lane = tid & 63;
    int l16 = lane & 15, quad = lane >> 4;
    int wc = wave;                       // wave's 32-col slice
    // XCD swizzle: x-major logical order, contiguous chunk per XCD
    int gx = gridDim.x, gy = gridDim.y;
    int p = blockIdx.y * gx + blockIdx.x;
    int cpx = (gx * gy) >> 3;
    int L = (p & 7) * cpx + (p >> 3);
    int bx = L / gy, by = L % gy;
    int m0 = by * 64, n0 = bx * 128;
    int Ksp = K / gridDim.z;             // split-K span (z=1 -> full K)
    int kbeg = blockIdx.z * Ksp;
    int nt = Ksp >> 6;                   // 8 or 16, always even

    // staging coords: thread -> (row, 16B chunk); lanes sweep ch -> 128B runs
    int trow = tid >> 3, ch = tid & 7;
    const ushort* agp0 = A  + (size_t)(m0 + trow) * K + kbeg + ch * 8;
    const ushort* agp1 = A  + (size_t)(m0 + 32 + trow) * K + kbeg + ch * 8;
    const ushort* bgp0 = Bt + (size_t)(n0 + trow) * K + kbeg + ch * 8;
    const ushort* bgp1 = Bt + (size_t)(n0 + 32 + trow) * K + kbeg + ch * 8;
    const ushort* bgp2 = Bt + (size_t)(n0 + 64 + trow) * K + kbeg + ch * 8;
    const ushort* bgp3 = Bt + (size_t)(n0 + 96 + trow) * K + kbeg + ch * 8;
    int aw0 = trow * 72 + ch * 8, aw1 = (32 + trow) * 72 + ch * 8;
    int bw0 = trow * 72 + ch * 8, bw1 = (32 + trow) * 72 + ch * 8;
    int bw2 = (64 + trow) * 72 + ch * 8, bw3 = (96 + trow) * 72 + ch * 8;

    short8 pa00, pa01, pb00, pb01, pb02, pb03;   // prefetch set 0
    short8 pa10, pa11, pb10, pb11, pb12, pb13;   // prefetch set 1
    f32x4 acc[4][2] = {};

    GISSUE(0, 0);        // tile 0 -> set 0
    GISSUE(1, 64);       // tile 1 -> set 1
    GWRITE(0, 0);        // buf0 <- tile 0 (auto vmcnt waits set0 only)
    GSYNC();
    for (int t = 0; t < nt; t += 2) {
        // even phase: cur buf0 = tile t
        if (t + 2 < nt) GISSUE(0, (t + 2) << 6);
        __builtin_amdgcn_sched_barrier(0);
        GCOMPUTE(0);
        if (t + 1 < nt) GWRITE(1, 1);    // buf1 <- tile t+1
        GSYNC();
        // odd phase: cur buf1 = tile t+1
        if (t + 3 < nt) GISSUE(1, (t + 3) << 6);
        __builtin_amdgcn_sched_barrier(0);
        if (t + 1 < nt) GCOMPUTE(1);
        if (t + 2 < nt) GWRITE(0, 0);    // buf0 <- tile t+2
        GSYNC();
    }
    // epilogue: C frag layout col=l16, row=quad*4+r
    float* oP = (EPI == EPI_F32PART && blockIdx.z == 1) ? outF2 : outF;
    #pragma unroll
    for (int i = 0; i < 4; i++) {
        int row_base = m0 + i * 16 + quad * 4;
        #pragma unroll
        for (int j = 0; j < 2; j++) {
            int col = n0 + wc * 32 + j * 16 + l16;
            float bvf = (EPI == EPI_F32PART) ? 0.f : bias[col];
            #pragma unroll
            for (int r = 0; r < 4; r++) {
                int row = row_base + r;
                float v = acc[i][j][r] + bvf;
                if constexpr (EPI == EPI_F32RES) {
                    outF[(size_t)row * N + col] = v + resid[(size_t)row * N + col];
                } else if constexpr (EPI == EPI_F32PART) {
                    oP[(size_t)row * N + col] = v;
                } else if constexpr (EPI == EPI_GELU) {
                    float gg = 0.5f * v * (1.0f + erff(v * 0.70710678118654752f));
                    outB[(size_t)row * N + col] = f2bf(gg);
                } else {
                    outB[(size_t)row * N + col] = f2bf(v);
                }
            }
        }
    }
}

// ---------------------------------------------------------------------------
// Flash attention, split-K in block, swapped-operand QK^T (round-9 version,
// best measured 48.7 us -- byte-identical).
__global__ __launch_bounds__(512) void flash_kernel(const ushort* __restrict__ qkv,
        ushort* __restrict__ o) {
    __shared__ __align__(16) char smem[47232];
    auto Ks  = (ushort (*)[64][72])smem;              // [kh][key][d]   18432 B
    auto Vt  = (ushort (*)[4640])(smem + 18432);      // [kh][VT(d,key)] 18560 B
    auto Pt  = (ushort (*)[16][40])(smem + 36992);    // [wave][q][32key+pad] 10240 B
    auto cbuf = (float (*)[18][64])smem;              // combine buffer (aliased)
    // VT(d,key) = d*72 + (d>>4)*8 + key

    int tid = threadIdx.x;
    int wave = tid >> 6, lane = tid & 63;
    int kh = wave >> 2;          // key half this wave owns
    int wq = wave & 3;           // 16-q-row group
    int l16 = lane & 15, quad = lane >> 4;
    int bidx = blockIdx.x;
    int qt = bidx & 31;
    int h = (bidx >> 5) & 7;
    int b = bidx >> 8;
    int q0 = qt * 64;
    const size_t base = (size_t)b * 2048 * 1536;

    int htid = tid & 255;
    int srow = htid >> 2;            // key row 0..63
    int sg   = htid & 3;             // d-chunk 0..3
    int sdb  = sg * 16;
    const ushort* kgbase = qkv + base + 512  + h * 64 + sdb;
    const ushort* vgbase = qkv + base + 1024 + h * 64 + sdb;
    int vldsoff = sdb * 72 + sg * 8 + srow;

    short8 aq[2];
    {
        int qrow = q0 + wq * 16 + l16;
        const ushort* qp = qkv + base + (size_t)qrow * 1536 + h * 64;
        aq[0] = *(const short8*)(qp + quad * 8);
        aq[1] = *(const short8*)(qp + 32 + quad * 8);
    }
    f32x4 accO[4] = {};
    float mrow = -INFINITY, lrow = 0.f;   // per-lane state for q = l16

    {   // prologue: stage tile 0
        int kb = kh * 1024;
        const ushort* kp = kgbase + (size_t)(kb + srow) * 1536;
        short8 k0 = *(const short8*)kp;
        short8 k1 = *(const short8*)(kp + 8);
        const ushort* vp = vgbase + (size_t)(kb + srow) * 1536;
        short8 v0 = *(const short8*)vp;
        short8 v1 = *(const short8*)(vp + 8);
        *(short8*)&Ks[kh][srow][sdb]     = k0;
        *(short8*)&Ks[kh][srow][sdb + 8] = k1;
        #pragma unroll
        for (int i = 0; i < 8; i++) Vt[kh][vldsoff + i * 72] = (ushort)v0[i];
        #pragma unroll
        for (int i = 0; i < 8; i++) Vt[kh][vldsoff + (8 + i) * 72] = (ushort)v1[i];
    }
    __syncthreads();

    for (int it = 0; it < 16; ++it) {
        short8 nk0, nk1, nv0, nv1;
        bool pre = (it < 15);
        if (pre) {   // prefetch next tile -> regs; latency hides under compute
            int kb = kh * 1024 + (it + 1) * 64;
            const ushort* kp = kgbase + (size_t)(kb + srow) * 1536;
            nk0 = *(const short8*)kp;
            nk1 = *(const short8*)(kp + 8);
            const ushort* vp = vgbase + (size_t)(kb + srow) * 1536;
            nv0 = *(const short8*)vp;
            nv1 = *(const short8*)(vp + 8);
        }
        // S^T = K Q^T : lane (l16,quad) gets S[key=s*16+quad*4+r][q=l16]
        f32x4 sacc[4] = {};
        __builtin_amdgcn_s_setprio(1);
        #pragma unroll
        for (int c = 0; c < 2; c++) {
            #pragma unroll
            for (int s = 0; s < 4; s++) {
                short8 kf = *(short8*)&Ks[kh][s * 16 + l16][c * 32 + quad * 8];
                sacc[s] = __builtin_amdgcn_mfma_f32_16x16x32_bf16(kf, aq[c], sacc[s], 0, 0, 0);
            }
        }
        __builtin_amdgcn_s_setprio(0);
        // online softmax: per-lane row, reduce across the 4 quads
        float tm = sacc[0][0];
        #pragma unroll
        for (int s = 0; s < 4; s++)
            #pragma unroll
            for (int r = 0; r < 4; r++) tm = fmaxf(tm, sacc[s][r]);
        tm = fmaxf(tm, __shfl_xor(tm, 16, 64));
        tm = fmaxf(tm, __shfl_xor(tm, 32, 64));
        float mn = fmaxf(mrow, tm * 0.125f);
        float al = __expf(mrow - mn);
        float rsum = 0.f;
        ushort4v w4[4];
        #pragma unroll
        for (int s = 0; s < 4; s++)
            #pragma unroll
            for (int r = 0; r < 4; r++) {
                float pv = __expf(sacc[s][r] * 0.125f - mn);
                rsum += pv;
                w4[s][r] = f2bf(pv);
            }
        rsum += __shfl_xor(rsum, 16, 64);
        rsum += __shfl_xor(rsum, 32, 64);
        lrow = lrow * al + rsum;
        mrow = mn;
        #pragma unroll
        for (int s = 0; s < 4; s++)
            #pragma unroll
            for (int r = 0; r < 4; r++) accO[s][r] *= al;
        // P -> Pt (packed b64), double-pumped half tile; PV = mfma(V^T, P)
        *(ushort4v*)&Pt[wave][l16][quad * 4]      = w4[0];
        *(ushort4v*)&Pt[wave][l16][16 + quad * 4] = w4[1];
        {
            short8 ap = *(short8*)&Pt[wave][l16][quad * 8];
            __builtin_amdgcn_s_setprio(1);
            #pragma unroll
            for (int s = 0; s < 4; s++) {
                short8 vf = *(short8*)&Vt[kh][(s * 16 + l16) * 72 + s * 8 + quad * 8];
                accO[s] = __builtin_amdgcn_mfma_f32_16x16x32_bf16(vf, ap, accO[s], 0, 0, 0);
            }
            __builtin_amdgcn_s_setprio(0);
        }
        *(ushort4v*)&Pt[wave][l16][quad * 4]      = w4[2];
        *(ushort4v*)&Pt[wave][l16][16 + quad * 4] = w4[3];
        {
            short8 ap = *(short8*)&Pt[wave][l16][quad * 8];
            __builtin_amdgcn_s_setprio(1);
            #pragma unroll
            for (int s = 0; s < 4; s++) {
                short8 vf = *(short8*)&Vt[kh][(s * 16 + l16) * 72 + s * 8 + 32 + quad * 8];
                accO[s] = __builtin_amdgcn_mfma_f32_16x16x32_bf16(vf, ap, accO[s], 0, 0, 0);
            }
            __builtin_amdgcn_s_setprio(0);
        }
        __syncthreads();   // all waves done reading Ks/Vt tile it
        if (pre) {
            *(short8*)&Ks[kh][srow][sdb]     = nk0;
            *(short8*)&Ks[kh][srow][sdb + 8] = nk1;
            #pragma unroll
            for (int i = 0; i < 8; i++) Vt[kh][vldsoff + i * 72] = (ushort)nv0[i];
            #pragma unroll
            for (int i = 0; i < 8; i++) Vt[kh][vldsoff + (8 + i) * 72] = (ushort)nv1[i];
        }
        __syncthreads();
    }
    // ---- merge key-half partials (wave w with wave w+4); state is per-lane ----
    if (kh == 1) {
        cbuf[wq][0][lane] = mrow;
        cbuf[wq][1][lane] = lrow;
        #pragma unroll
        for (int s = 0; s < 4; s++)
            #pragma unroll
            for (int r = 0; r < 4; r++)
                cbuf[wq][2 + s * 4 + r][lane] = accO[s][r];
    }
    __syncthreads();
    if (kh == 0) {
        float m1 = cbuf[wq][0][lane];
        float l1 = cbuf[wq][1][lane];
        float mn = fmaxf(mrow, m1);
        float a0 = __expf(mrow - mn);
        float a1 = __expf(m1 - mn);
        float rl = 1.0f / (lrow * a0 + l1 * a1);
        int qrow = q0 + wq * 16 + l16;
        #pragma unroll
        for (int s = 0; s < 4; s++) {
            ushort4v ov4;
            #pragma unroll
            for (int r = 0; r < 4; r++) {
                float ov = (accO[s][r] * a0 + cbuf[wq][2 + s * 4 + r][lane] * a1) * rl;
                ov4[r] = f2bf(ov);
            }
            *(ushort4v*)&o[((size_t)(b * 2048 + qrow)) * 512 + h * 64 + s * 16 + quad * 4] = ov4;
        }
    }
}

// ---------------------------------------------------------------------------
// Output transpose + split-K combine: x = x2 + pA + pB + b2 (f32), then
// transpose [token][c] -> out[b,t,c,l]. LDS tiled 32x32.
__global__ __launch_bounds__(256) void tout_kernel(const float* __restrict__ x2,
        const float* __restrict__ pA, const float* __restrict__ pB,
        const float* __restrict__ b2, float* __restrict__ out) {
    __shared__ float tile[32][33];
    int bt = blockIdx.z;
    int l0 = blockIdx.y * 32;
    int c0 = blockIdx.x * 32;
    int tx = threadIdx.x, ty = threadIdx.y;   // 32 x 8
    float bv = b2[c0 + tx];
    #pragma unroll
    for (int i = 0; i < 4; i++) {
        int l = ty + i * 8;
        size_t idx = ((size_t)bt * 256 + l0 + l) * 512 + c0 + tx;
        tile[l][tx] = x2[idx] + pA[idx] + pB[idx] + bv;
    }
    __syncthreads();
    #pragma unroll
    for (int i = 0; i < 4; i++) {
        int cc = ty + i * 8;
        out[((size_t)bt * 512 + c0 + cc) * 256 + l0 + tx] = tile[tx][cc];
    }
}

// ---------------------------------------------------------------------------
extern "C" void kernel_launch(void* const* d_in, const int* in_sizes, int n_in,
                              void* d_out, int out_size, void* d_ws, size_t ws_size,
                              hipStream_t stream) {
    const float* in_feat = (const float*)d_in[0];
    const float* qkv_w  = (const float*)d_in[1];
    const float* qkv_b  = (const float*)d_in[2];
    const float* proj_w = (const float*)d_in[3];
    const float* proj_b = (const float*)d_in[4];
    const float* ln1_g  = (const float*)d_in[5];
    const float* ln1_b  = (const float*)d_in[6];
    const float* w1     = (const float*)d_in[7];
    const float* b1     = (const float*)d_in[8];
    const float* w2     = (const float*)d_in[9];
    const float* b2     = (const float*)d_in[10];
    const float* ln2_g  = (const float*)d_in[11];
    const float* ln2_b  = (const float*)d_in[12];

    char* ws = (char*)d_ws;
    float*  x    = (float*) (ws);              // 8 MB residual 1
    float*  x2   = (float*) (ws + 8388608);    // 8 MB residual 2
    ushort* xln  = (ushort*)(ws + 16777216);   // 4 MB LN1 out
    ushort* h2   = (ushort*)(ws + 20971520);   // 4 MB LN2 out
    ushort* ao   = (ushort*)(ws + 25165824);   // 4 MB attention out
    ushort* qkv  = (ushort*)(ws + 29360128);   // 12 MB qkv
    ushort* gbuf = (ushort*)(ws + 41943040);   // 16 MB MLP hidden

    // split-K partials for MLP-down: reuse dead regions (x dead after proj;
    // xln+h2 dead after QKV/up respectively)
    float* pA = (float*)(ws);                  // 8 MB over x
    float* pB = (float*)(ws + 16777216);       // 8 MB over xln+h2

    // bf16-transposed weights live in d_out (overwritten by tout at step 8)
    char* scr = (char*)d_out;
    ushort* qkvT = (ushort*)(scr);             // 1.5 MB
    ushort* projT = (ushort*)(scr + 1572864);  // 0.5 MB
    ushort* w1T  = (ushort*)(scr + 2097152);   // 2 MB
    ushort* w2T  = (ushort*)(scr + 4194304);   // 2 MB

    wtrans_kernel<<<3072, 256, 0, stream>>>(qkv_w, qkvT, proj_w, projT,
                                            w1, w1T, w2, w2T);
    prep_kernel<<<4096, 512, 0, stream>>>(in_feat, ln1_g, ln1_b, x, xln);
    // QKV: 64x128 tiles -> 768 blocks
    gemm_kernel<EPI_BF16><<<dim3(12, 64), 256, 0, stream>>>(
        xln, qkvT, qkv_b, nullptr, nullptr, nullptr, qkv, 4096, 1536, 512);
    flash_kernel<<<512, 512, 0, stream>>>(qkv, ao);
    // proj + residual: 256 blocks
    gemm_kernel<EPI_F32RES><<<dim3(4, 64), 256, 0, stream>>>(
        ao, projT, proj_b, x, x2, nullptr, nullptr, 4096, 512, 512);
    ln2_kernel<<<4096, 512, 0, stream>>>(x2, ln2_g, ln2_b, h2);
    // MLP up + GELU: 1024 blocks
    gemm_kernel<EPI_GELU><<<dim3(16, 64), 256, 0, stream>>>(
        h2, w1T, b1, nullptr, nullptr, nullptr, gbuf, 4096, 2048, 512);
    // MLP down, split-K2: 512 blocks, f32 partials combined in tout
    gemm_kernel<EPI_F32PART><<<dim3(4, 64, 2), 256, 0, stream>>>(
        gbuf, w2T, nullptr, nullptr, pA, pB, nullptr, 4096, 512, 2048);
    // output transpose + combine (x2 + pA + pB + b2)
    tout_kernel<<<dim3(16, 8, 16), dim3(32, 8), 0, stream>>>(
        x2, pA, pB, b2, (float*)d_out);
}